// Round 10
// baseline (194.122 us; speedup 1.0000x reference)
//
#include <hip/hip_runtime.h>
#include <stdint.h>

// MatrixKAN as dense bf16 MFMA GEMM over expanded interpolation basis.
// Per feature slots [0..20]=hat (2 nonzero), 21=silu(xc) (pairs base_w), 22..23=pad.
// K = 512*24 = 12288. Plane-major LDS tiles (plane = 16B chunk column of 128 rows,
// stride 2048B): conflict-free for linear global_load_lds DMA and 16-row frag reads.
// BK=96 (4 features, 12 chunks, 3 K32-steps), 48KB LDS -> 3 blocks/CU.
// KSPLIT=3: 768 blocks = exactly 3/CU, one packed round. bf16 split-K partials.
// R10: A-staging via zero-fill (3x ds_write_b128 of const 0, no VALU) + 3x
// ds_write_b16 scatter (w0@idx, w1@idx+1, silu@21) -- replaces build_strip's
// ~140 VALU/thread-iter on the barrier-critical staging path with ~30.
// No fences (R7 lesson), no NT stores (R5 lesson).

typedef short v8s __attribute__((ext_vector_type(8)));
typedef float v4f __attribute__((ext_vector_type(4)));

#define B_DIM 8192
#define IN_DIM 512
#define OUT_DIM 512
#define G_DIM 20
#define FPT 4                        // features per K-tile
#define KT_TOTAL (IN_DIM / FPT)      // 128 K-tiles
#define KSPLIT 3
#define BM 128
#define BN 128
#define CHUNKS 12                    // 16B chunks per tile-row (3 per feature)
#define PLANE 2048                   // 128 rows * 16B per chunk-plane
#define TILE_BYTES (CHUNKS * PLANE)  // 24 KB

#define P_BYTES ((size_t)IN_DIM * B_DIM * 8)                          // 33.55 MB
#define WT_BYTES ((size_t)(OUT_DIM / BN) * KT_TOTAL * TILE_BYTES)     // 12.58 MB
#define PART_ELEMS ((size_t)B_DIM * OUT_DIM)
#define WS_NEED (P_BYTES + WT_BYTES + (size_t)KSPLIT * PART_ELEMS * 2)

#define PACK_BLKS ((B_DIM / 64) * (IN_DIM / 64))   // 1024
#define WPACK_BLKS ((OUT_DIM * IN_DIM) / 256)      // 1024

static __device__ __forceinline__ unsigned f2bf(float f) {
  unsigned u = __builtin_bit_cast(unsigned, f);
  return (u + 0x7fffu + ((u >> 16) & 1u)) >> 16;   // RNE bf16
}

static __device__ __forceinline__ float bflo(unsigned u) {   // bf16 in low 16
  return __builtin_bit_cast(float, u << 16);
}
static __device__ __forceinline__ float bfhi(unsigned u) {   // bf16 in high 16
  return __builtin_bit_cast(float, u & 0xffff0000u);
}

static __device__ __forceinline__ void load16(const void* g, void* l) {
  __builtin_amdgcn_global_load_lds(
      (const __attribute__((address_space(1))) unsigned*)g,
      (__attribute__((address_space(3))) unsigned*)l, 16, 0, 0);
}

__global__ void zero_out_kernel(uint4* __restrict__ out) {
  out[(size_t)blockIdx.x * 256 + threadIdx.x] = uint4{0u, 0u, 0u, 0u};
}

// Fused input-pack. Blocks [0, PACK_BLKS): x[b][i] -> P[i][b] packed
// {.x = bf16(1-t)|bf16(t)<<16, .y = idx|bf16(silu)<<16} via LDS transpose.
// Blocks [PACK_BLKS, +WPACK_BLKS): coeffs/base_w -> Wt plane-major 24KB slabs
// (slab (n_blk,kt): plane 3f+cf = slots 8cf..8cf+7 of feature kt*4+f, row=o&127).
__global__ void pack_fused_kernel(const float* __restrict__ x, uint2* __restrict__ P,
                                  const float* __restrict__ coeffs,
                                  const float* __restrict__ base_w,
                                  char* __restrict__ Wt) {
  __shared__ uint2 tile[64 * 65];
  const int t = threadIdx.x;
  if (blockIdx.x < PACK_BLKS) {
    const int b0 = (blockIdx.x & (B_DIM / 64 - 1)) * 64;
    const int i0 = (blockIdx.x / (B_DIM / 64)) * 64;
    const int tr = t >> 6;
    const int tc = t & 63;
#pragma unroll
    for (int it = 0; it < 16; ++it) {
      int br = it * 4 + tr;
      float xv = x[(size_t)(b0 + br) * IN_DIM + i0 + tc];
      float xc = fminf(fmaxf(xv, -1.0f), 1.0f);
      float xg = (xc + 1.0f) * 10.0f;           // (xc+1)*0.5*G
      int idx = (int)floorf(xg);
      idx = idx < 0 ? 0 : (idx > G_DIM - 1 ? G_DIM - 1 : idx);
      float tt = xg - (float)idx;
      float sl = xc / (1.0f + __expf(-xc));     // silu(clipped x)
      uint2 pv;
      pv.x = f2bf(1.0f - tt) | (f2bf(tt) << 16);
      pv.y = (unsigned)idx | (f2bf(sl) << 16);
      tile[tc * 65 + br] = pv;
    }
    __syncthreads();
#pragma unroll
    for (int it = 0; it < 16; ++it) {
      int ir = it * 4 + tr;
      P[(size_t)(i0 + ir) * B_DIM + b0 + tc] = tile[ir * 65 + tc];
    }
  } else {
    const unsigned u = (blockIdx.x - PACK_BLKS) * 256 + t;
    const int s = u >> 9;            // slab = n_blk*KT_TOTAL + kt
    const int w = u & 511;
    const int row = w >> 2;          // o & 127
    const int f = w & 3;
    const int n_blk = s / KT_TOTAL;
    const int kt = s - n_blk * KT_TOTAL;
    const int o = n_blk * 128 + row;
    const int i = kt * 4 + f;
    const size_t g = (size_t)o * IN_DIM + i;
    const float* c = coeffs + g * 21;
    float cf[21];
#pragma unroll
    for (int j = 0; j < 21; ++j) cf[j] = c[j];
    float bw = base_w[g];
    unsigned d[12];
#pragma unroll
    for (int j = 0; j < 10; ++j) d[j] = f2bf(cf[2 * j]) | (f2bf(cf[2 * j + 1]) << 16);
    d[10] = f2bf(cf[20]) | (f2bf(bw) << 16);  // slots 20, 21(=base_w)
    d[11] = 0u;                               // slots 22,23 pad
    char* slab = Wt + (size_t)s * TILE_BYTES;
#pragma unroll
    for (int p = 0; p < 3; ++p)
      *(uint4*)(slab + (3 * f + p) * PLANE + row * 16) =
          uint4{d[4 * p], d[4 * p + 1], d[4 * p + 2], d[4 * p + 3]};
  }
}

// out = p0+p1+p2: bf16 partial streams (8 per uint4), fp32 accumulate + store.
__global__ void reduce_kernel(const uint4* __restrict__ p, v4f* __restrict__ out) {
  size_t i = (size_t)blockIdx.x * 256 + threadIdx.x;
  const size_t q = PART_ELEMS / 8;
  uint4 a = p[i], b = p[i + q], c = p[i + 2 * q];
  v4f lo, hi;
  lo[0] = bflo(a.x) + bflo(b.x) + bflo(c.x);
  hi[0] = bfhi(a.x) + bfhi(b.x) + bfhi(c.x);
  lo[1] = bflo(a.y) + bflo(b.y) + bflo(c.y);
  hi[1] = bfhi(a.y) + bfhi(b.y) + bfhi(c.y);
  lo[2] = bflo(a.z) + bflo(b.z) + bflo(c.z);
  hi[2] = bfhi(a.z) + bfhi(b.z) + bfhi(c.z);
  lo[3] = bflo(a.w) + bflo(b.w) + bflo(c.w);
  hi[3] = bfhi(a.w) + bfhi(b.w) + bfhi(c.w);
  v4f o0 = {lo[0], hi[0], lo[1], hi[1]};
  v4f o1 = {lo[2], hi[2], lo[3], hi[3]};
  out[2 * i] = o0;
  out[2 * i + 1] = o1;
}

// Stage one feature strip (row owned by this lane): zero-fill 3 planes (b128,
// const 0, fixed conflict-free addresses), then scatter w0@idx, w1@idx+1,
// silu@21 as ds_write_b16. Bit-identical to the old build_strip result.
static __device__ __forceinline__ void stage_strip(char* abase, uint2 pv) {
  const uint4 zz = {0u, 0u, 0u, 0u};
#pragma unroll
  for (int p = 0; p < 3; ++p) *(uint4*)(abase + p * PLANE) = zz;
  const int idx = (int)(pv.y & 0xffffu);
  const int s1 = idx + 1;
  *(unsigned short*)(abase + ((idx >> 3) << 11) + ((idx & 7) << 1)) =
      (unsigned short)pv.x;
  *(unsigned short*)(abase + ((s1 >> 3) << 11) + ((s1 & 7) << 1)) =
      (unsigned short)(pv.x >> 16);
  *(unsigned short*)(abase + 2 * PLANE + 10) = (unsigned short)(pv.y >> 16);
}

template <bool ATOMIC>
__global__ __launch_bounds__(256, 3) void kan_gemm(const uint2* __restrict__ P,
                                                   const char* __restrict__ Wt,
                                                   unsigned short* __restrict__ part,
                                                   float* __restrict__ outA) {
  __shared__ uint4 lds4[(2 * TILE_BYTES) / 16];   // 24KB A + 24KB B (plane-major)
  char* Ab = (char*)lds4;
  char* Bb = (char*)lds4 + TILE_BYTES;
  const int t = threadIdx.x;
  const int lane = t & 63;
  const int wv = t >> 6;               // 4 waves, 2x2 grid of 64x64 tiles
  const int wm = wv >> 1, wn = wv & 1;
  const int b0 = blockIdx.x * BM;
  const int n_blk = blockIdx.y;
  const int z = blockIdx.z;
  const int kt0 = (z * KT_TOTAL) / KSPLIT;          // 0,42,85
  const int ktend = ((z + 1) * KT_TOTAL) / KSPLIT;  // 42,85,128

  v4f acc[4][4];
  const v4f z4 = {0.f, 0.f, 0.f, 0.f};
#pragma unroll
  for (int ii = 0; ii < 4; ++ii)
#pragma unroll
    for (int jj = 0; jj < 4; ++jj) acc[ii][jj] = z4;

  // A-gen: wave wv owns feature wv (planes 3wv..3wv+2); lane owns rows lane, lane+64
  char* abase0 = Ab + 3 * wv * PLANE + lane * 16;
  char* abase1 = Ab + 3 * wv * PLANE + (lane + 64) * 16;
  uint2 pv0 = P[(size_t)(kt0 * 4 + wv) * B_DIM + b0 + lane];
  uint2 pv1 = P[(size_t)(kt0 * 4 + wv) * B_DIM + b0 + lane + 64];

  const int r16 = lane & 15;
  const int q16 = lane >> 4;

  for (int kt = kt0; kt < ktend; ++kt) {
    __syncthreads();   // previous compute done; safe to overwrite tiles

    // B tile: 24KB linear DMA (plane-major slab, lane-linear LDS dst)
    const char* wsrc = Wt + (size_t)(n_blk * KT_TOTAL + kt) * TILE_BYTES;
#pragma unroll
    for (int q = 0; q < 6; ++q)
      load16(wsrc + (q * 256 + t) * 16, Bb + (q * 256 + t) * 16);

    // prefetch next P (in flight across barrier + compute)
    const int ktn = (kt + 1 < ktend) ? kt + 1 : kt;
    uint2 pn0 = P[(size_t)(ktn * 4 + wv) * B_DIM + b0 + lane];
    uint2 pn1 = P[(size_t)(ktn * 4 + wv) * B_DIM + b0 + lane + 64];

    // stage 2 A strips: zero-fill + b16 scatters (program-order per lane)
    stage_strip(abase0, pv0);
    stage_strip(abase1, pv1);
    pv0 = pn0;
    pv1 = pn1;

    __syncthreads();   // drains DMA (vmcnt) + A writes (lgkm)

    // compute: 3 K32-steps, 16 MFMA each per wave
#pragma unroll
    for (int s = 0; s < 3; ++s) {
      const int chunk = s * 4 + q16;   // plane index; k = chunk*8 + j
      v8s af[4], bfr[4];
#pragma unroll
      for (int rm = 0; rm < 4; ++rm) {
        int row = wm * 64 + rm * 16 + r16;
        af[rm] = *(const v8s*)(Ab + chunk * PLANE + row * 16);
      }
#pragma unroll
      for (int cn = 0; cn < 4; ++cn) {
        int row = wn * 64 + cn * 16 + r16;
        bfr[cn] = *(const v8s*)(Bb + chunk * PLANE + row * 16);
      }
#pragma unroll
      for (int rm = 0; rm < 4; ++rm)
#pragma unroll
        for (int cn = 0; cn < 4; ++cn)
          acc[rm][cn] = __builtin_amdgcn_mfma_f32_16x16x32_bf16(af[rm], bfr[cn], acc[rm][cn], 0, 0, 0);
    }
  }

  // epilogue: C/D layout col=lane&15, row=(lane>>4)*4+reg (verified m89/m91)
  const int q4 = (lane >> 4) * 4;
  if (ATOMIC) {
#pragma unroll
    for (int rm = 0; rm < 4; ++rm)
#pragma unroll
      for (int cn = 0; cn < 4; ++cn)
#pragma unroll
        for (int r = 0; r < 4; ++r) {
          int row = b0 + wm * 64 + rm * 16 + q4 + r;
          int col = n_blk * BN + wn * 64 + cn * 16 + r16;
          atomicAdd(outA + (size_t)row * OUT_DIM + col, acc[rm][cn][r]);
        }
  } else {
    // bf16 partials: half the split-K write traffic; reduce re-expands to fp32
    unsigned short* mypart = part + (size_t)z * PART_ELEMS;
#pragma unroll
    for (int rm = 0; rm < 4; ++rm)
#pragma unroll
      for (int cn = 0; cn < 4; ++cn)
#pragma unroll
        for (int r = 0; r < 4; ++r) {
          int row = b0 + wm * 64 + rm * 16 + q4 + r;
          int col = n_blk * BN + wn * 64 + cn * 16 + r16;
          mypart[(size_t)row * OUT_DIM + col] = (unsigned short)f2bf(acc[rm][cn][r]);
        }
  }
}

extern "C" void kernel_launch(void* const* d_in, const int* in_sizes, int n_in,
                              void* d_out, int out_size, void* d_ws, size_t ws_size,
                              hipStream_t stream) {
  const float* x = (const float*)d_in[0];
  const float* coeffs = (const float*)d_in[1];
  const float* base_w = (const float*)d_in[2];
  float* out = (float*)d_out;

  uint2* P = (uint2*)d_ws;
  char* Wt = (char*)d_ws + P_BYTES;
  unsigned short* part = (unsigned short*)((char*)d_ws + P_BYTES + WT_BYTES);

  pack_fused_kernel<<<PACK_BLKS + WPACK_BLKS, 256, 0, stream>>>(x, P, coeffs, base_w, Wt);

  if (ws_size >= WS_NEED) {
    kan_gemm<false><<<dim3(B_DIM / BM, OUT_DIM / BN, KSPLIT), 256, 0, stream>>>(P, Wt, part, out);
    reduce_kernel<<<(int)(PART_ELEMS / 8 / 256), 256, 0, stream>>>((const uint4*)part, (v4f*)out);
  } else {
    zero_out_kernel<<<(int)((PART_ELEMS * 4) / 4096), 256, 0, stream>>>((uint4*)out);
    kan_gemm<true><<<dim3(B_DIM / BM, OUT_DIM / BN, KSPLIT), 256, 0, stream>>>(P, Wt, part, out);
  }
}

// Round 11
// 180.522 us; speedup vs baseline: 1.0753x; 1.0753x over previous
//
#include <hip/hip_runtime.h>
#include <stdint.h>

// MatrixKAN as dense bf16 MFMA GEMM over expanded interpolation basis.
// Per feature slots [0..20]=hat (2 nonzero), 21=silu(xc) (pairs base_w), 22..23=pad.
// K = 512*24 = 12288. Plane-major tiles (plane = 16B chunk column of 128 rows).
// R11: kernel was LDS-pipe-BW-bound (R10: VALUBusy 40->20 with zero dur change;
// 150KB/iter LDS traffic ~= 94us floor at 85B/cyc). B fragments now load
// DIRECTLY from global Wt (slab layout == frag layout; L1/L2-served, wave pairs
// and same-(y,z) blocks reuse lines) -- removes B DMA (24KB/iter LDS writes)
// and B frag ds_reads (49KB/iter): LDS/iter 150->77KB. LDS = 24KB A tile only.
// A staged via zero-fill b128 + 3x b16 scatter (R10). bf16 split-K partials.
// KSPLIT=3: 768 blocks = 3/CU packed. No fences (R7), no NT stores (R5).

typedef short v8s __attribute__((ext_vector_type(8)));
typedef float v4f __attribute__((ext_vector_type(4)));

#define B_DIM 8192
#define IN_DIM 512
#define OUT_DIM 512
#define G_DIM 20
#define FPT 4                        // features per K-tile
#define KT_TOTAL (IN_DIM / FPT)      // 128 K-tiles
#define KSPLIT 3
#define BM 128
#define BN 128
#define CHUNKS 12                    // 16B chunks per tile-row (3 per feature)
#define PLANE 2048                   // 128 rows * 16B per chunk-plane
#define TILE_BYTES (CHUNKS * PLANE)  // 24 KB

#define P_BYTES ((size_t)IN_DIM * B_DIM * 8)                          // 33.55 MB
#define WT_BYTES ((size_t)(OUT_DIM / BN) * KT_TOTAL * TILE_BYTES)     // 12.58 MB
#define PART_ELEMS ((size_t)B_DIM * OUT_DIM)
#define WS_NEED (P_BYTES + WT_BYTES + (size_t)KSPLIT * PART_ELEMS * 2)

#define PACK_BLKS ((B_DIM / 64) * (IN_DIM / 64))   // 1024
#define WPACK_BLKS ((OUT_DIM * IN_DIM) / 256)      // 1024

static __device__ __forceinline__ unsigned f2bf(float f) {
  unsigned u = __builtin_bit_cast(unsigned, f);
  return (u + 0x7fffu + ((u >> 16) & 1u)) >> 16;   // RNE bf16
}

static __device__ __forceinline__ float bflo(unsigned u) {   // bf16 in low 16
  return __builtin_bit_cast(float, u << 16);
}
static __device__ __forceinline__ float bfhi(unsigned u) {   // bf16 in high 16
  return __builtin_bit_cast(float, u & 0xffff0000u);
}

__global__ void zero_out_kernel(uint4* __restrict__ out) {
  out[(size_t)blockIdx.x * 256 + threadIdx.x] = uint4{0u, 0u, 0u, 0u};
}

// Fused input-pack. Blocks [0, PACK_BLKS): x[b][i] -> P[i][b] packed
// {.x = bf16(1-t)|bf16(t)<<16, .y = idx|bf16(silu)<<16} via LDS transpose.
// Blocks [PACK_BLKS, +WPACK_BLKS): coeffs/base_w -> Wt plane-major 24KB slabs
// (slab (n_blk,kt): plane 3f+cf = slots 8cf..8cf+7 of feature kt*4+f, row=o&127).
__global__ void pack_fused_kernel(const float* __restrict__ x, uint2* __restrict__ P,
                                  const float* __restrict__ coeffs,
                                  const float* __restrict__ base_w,
                                  char* __restrict__ Wt) {
  __shared__ uint2 tile[64 * 65];
  const int t = threadIdx.x;
  if (blockIdx.x < PACK_BLKS) {
    const int b0 = (blockIdx.x & (B_DIM / 64 - 1)) * 64;
    const int i0 = (blockIdx.x / (B_DIM / 64)) * 64;
    const int tr = t >> 6;
    const int tc = t & 63;
#pragma unroll
    for (int it = 0; it < 16; ++it) {
      int br = it * 4 + tr;
      float xv = x[(size_t)(b0 + br) * IN_DIM + i0 + tc];
      float xc = fminf(fmaxf(xv, -1.0f), 1.0f);
      float xg = (xc + 1.0f) * 10.0f;           // (xc+1)*0.5*G
      int idx = (int)floorf(xg);
      idx = idx < 0 ? 0 : (idx > G_DIM - 1 ? G_DIM - 1 : idx);
      float tt = xg - (float)idx;
      float sl = xc / (1.0f + __expf(-xc));     // silu(clipped x)
      uint2 pv;
      pv.x = f2bf(1.0f - tt) | (f2bf(tt) << 16);
      pv.y = (unsigned)idx | (f2bf(sl) << 16);
      tile[tc * 65 + br] = pv;
    }
    __syncthreads();
#pragma unroll
    for (int it = 0; it < 16; ++it) {
      int ir = it * 4 + tr;
      P[(size_t)(i0 + ir) * B_DIM + b0 + tc] = tile[ir * 65 + tc];
    }
  } else {
    const unsigned u = (blockIdx.x - PACK_BLKS) * 256 + t;
    const int s = u >> 9;            // slab = n_blk*KT_TOTAL + kt
    const int w = u & 511;
    const int row = w >> 2;          // o & 127
    const int f = w & 3;
    const int n_blk = s / KT_TOTAL;
    const int kt = s - n_blk * KT_TOTAL;
    const int o = n_blk * 128 + row;
    const int i = kt * 4 + f;
    const size_t g = (size_t)o * IN_DIM + i;
    const float* c = coeffs + g * 21;
    float cf[21];
#pragma unroll
    for (int j = 0; j < 21; ++j) cf[j] = c[j];
    float bw = base_w[g];
    unsigned d[12];
#pragma unroll
    for (int j = 0; j < 10; ++j) d[j] = f2bf(cf[2 * j]) | (f2bf(cf[2 * j + 1]) << 16);
    d[10] = f2bf(cf[20]) | (f2bf(bw) << 16);  // slots 20, 21(=base_w)
    d[11] = 0u;                               // slots 22,23 pad
    char* slab = Wt + (size_t)s * TILE_BYTES;
#pragma unroll
    for (int p = 0; p < 3; ++p)
      *(uint4*)(slab + (3 * f + p) * PLANE + row * 16) =
          uint4{d[4 * p], d[4 * p + 1], d[4 * p + 2], d[4 * p + 3]};
  }
}

// out = p0+p1+p2: bf16 partial streams (8 per uint4), fp32 accumulate + store.
__global__ void reduce_kernel(const uint4* __restrict__ p, v4f* __restrict__ out) {
  size_t i = (size_t)blockIdx.x * 256 + threadIdx.x;
  const size_t q = PART_ELEMS / 8;
  uint4 a = p[i], b = p[i + q], c = p[i + 2 * q];
  v4f lo, hi;
  lo[0] = bflo(a.x) + bflo(b.x) + bflo(c.x);
  hi[0] = bfhi(a.x) + bfhi(b.x) + bfhi(c.x);
  lo[1] = bflo(a.y) + bflo(b.y) + bflo(c.y);
  hi[1] = bfhi(a.y) + bfhi(b.y) + bfhi(c.y);
  lo[2] = bflo(a.z) + bflo(b.z) + bflo(c.z);
  hi[2] = bfhi(a.z) + bfhi(b.z) + bfhi(c.z);
  lo[3] = bflo(a.w) + bflo(b.w) + bflo(c.w);
  hi[3] = bfhi(a.w) + bfhi(b.w) + bfhi(c.w);
  v4f o0 = {lo[0], hi[0], lo[1], hi[1]};
  v4f o1 = {lo[2], hi[2], lo[3], hi[3]};
  out[2 * i] = o0;
  out[2 * i + 1] = o1;
}

// Stage one feature strip (row owned by this lane): zero-fill 3 planes (b128,
// const 0, fixed conflict-free addresses), then scatter w0@idx, w1@idx+1,
// silu@21 as ds_write_b16.
static __device__ __forceinline__ void stage_strip(char* abase, uint2 pv) {
  const uint4 zz = {0u, 0u, 0u, 0u};
#pragma unroll
  for (int p = 0; p < 3; ++p) *(uint4*)(abase + p * PLANE) = zz;
  const int idx = (int)(pv.y & 0xffffu);
  const int s1 = idx + 1;
  *(unsigned short*)(abase + ((idx >> 3) << 11) + ((idx & 7) << 1)) =
      (unsigned short)pv.x;
  *(unsigned short*)(abase + ((s1 >> 3) << 11) + ((s1 & 7) << 1)) =
      (unsigned short)(pv.x >> 16);
  *(unsigned short*)(abase + 2 * PLANE + 10) = (unsigned short)(pv.y >> 16);
}

template <bool ATOMIC>
__global__ __launch_bounds__(256, 3) void kan_gemm(const uint2* __restrict__ P,
                                                   const char* __restrict__ Wt,
                                                   unsigned short* __restrict__ part,
                                                   float* __restrict__ outA) {
  __shared__ uint4 lds4[TILE_BYTES / 16];   // 24KB A tile only (plane-major)
  char* Ab = (char*)lds4;
  const int t = threadIdx.x;
  const int lane = t & 63;
  const int wv = t >> 6;               // 4 waves, 2x2 grid of 64x64 tiles
  const int wm = wv >> 1, wn = wv & 1;
  const int b0 = blockIdx.x * BM;
  const int n_blk = blockIdx.y;
  const int z = blockIdx.z;
  const int kt0 = (z * KT_TOTAL) / KSPLIT;          // 0,42,85
  const int ktend = ((z + 1) * KT_TOTAL) / KSPLIT;  // 42,85,128

  v4f acc[4][4];
  const v4f z4 = {0.f, 0.f, 0.f, 0.f};
#pragma unroll
  for (int ii = 0; ii < 4; ++ii)
#pragma unroll
    for (int jj = 0; jj < 4; ++jj) acc[ii][jj] = z4;

  // A-gen: wave wv owns feature wv (planes 3wv..3wv+2); lane owns rows lane, lane+64
  char* abase0 = Ab + 3 * wv * PLANE + lane * 16;
  char* abase1 = Ab + 3 * wv * PLANE + (lane + 64) * 16;
  uint2 pv0 = P[(size_t)(kt0 * 4 + wv) * B_DIM + b0 + lane];
  uint2 pv1 = P[(size_t)(kt0 * 4 + wv) * B_DIM + b0 + lane + 64];

  const int r16 = lane & 15;
  const int q16 = lane >> 4;

  // B frag global addresses: uint4 index chunk*128 + row (row = wn*64+cn*16+r16)
  const uint4* wbase = (const uint4*)(Wt + (size_t)n_blk * KT_TOTAL * TILE_BYTES);
  int bidx[3][4];
#pragma unroll
  for (int s = 0; s < 3; ++s)
#pragma unroll
    for (int cn = 0; cn < 4; ++cn)
      bidx[s][cn] = (s * 4 + q16) * 128 + wn * 64 + cn * 16 + r16;

  for (int kt = kt0; kt < ktend; ++kt) {
    __syncthreads();   // previous compute done; safe to overwrite A tile

    // B frags for this kt: 12x buffer_load_dwordx4 straight from L1/L2
    // (latency hides under A staging; pre-compute barrier needs them anyway)
    const uint4* wsrc = wbase + (size_t)kt * (TILE_BYTES / 16);
    uint4 bv[3][4];
#pragma unroll
    for (int s = 0; s < 3; ++s)
#pragma unroll
      for (int cn = 0; cn < 4; ++cn)
        bv[s][cn] = wsrc[bidx[s][cn]];

    // prefetch next P (in flight across barrier + compute)
    const int ktn = (kt + 1 < ktend) ? kt + 1 : kt;
    uint2 pn0 = P[(size_t)(ktn * 4 + wv) * B_DIM + b0 + lane];
    uint2 pn1 = P[(size_t)(ktn * 4 + wv) * B_DIM + b0 + lane + 64];

    // stage 2 A strips: zero-fill + b16 scatters (program-order per lane)
    stage_strip(abase0, pv0);
    stage_strip(abase1, pv1);
    pv0 = pn0;
    pv1 = pn1;

    __syncthreads();   // drains A ds_writes (and the B/P loads)

    // compute: 3 K32-steps, 16 MFMA each per wave; A from LDS, B from regs
#pragma unroll
    for (int s = 0; s < 3; ++s) {
      const int chunk = s * 4 + q16;   // plane index; k = chunk*8 + j
      v8s af[4];
#pragma unroll
      for (int rm = 0; rm < 4; ++rm) {
        int row = wm * 64 + rm * 16 + r16;
        af[rm] = *(const v8s*)(Ab + chunk * PLANE + row * 16);
      }
#pragma unroll
      for (int rm = 0; rm < 4; ++rm)
#pragma unroll
        for (int cn = 0; cn < 4; ++cn)
          acc[rm][cn] = __builtin_amdgcn_mfma_f32_16x16x32_bf16(
              af[rm], __builtin_bit_cast(v8s, bv[s][cn]), acc[rm][cn], 0, 0, 0);
    }
  }

  // epilogue: C/D layout col=lane&15, row=(lane>>4)*4+reg (verified m89/m91)
  const int q4 = (lane >> 4) * 4;
  if (ATOMIC) {
#pragma unroll
    for (int rm = 0; rm < 4; ++rm)
#pragma unroll
      for (int cn = 0; cn < 4; ++cn)
#pragma unroll
        for (int r = 0; r < 4; ++r) {
          int row = b0 + wm * 64 + rm * 16 + q4 + r;
          int col = n_blk * BN + wn * 64 + cn * 16 + r16;
          atomicAdd(outA + (size_t)row * OUT_DIM + col, acc[rm][cn][r]);
        }
  } else {
    // bf16 partials: half the split-K write traffic; reduce re-expands to fp32
    unsigned short* mypart = part + (size_t)z * PART_ELEMS;
#pragma unroll
    for (int rm = 0; rm < 4; ++rm)
#pragma unroll
      for (int cn = 0; cn < 4; ++cn)
#pragma unroll
        for (int r = 0; r < 4; ++r) {
          int row = b0 + wm * 64 + rm * 16 + q4 + r;
          int col = n_blk * BN + wn * 64 + cn * 16 + r16;
          mypart[(size_t)row * OUT_DIM + col] = (unsigned short)f2bf(acc[rm][cn][r]);
        }
  }
}

extern "C" void kernel_launch(void* const* d_in, const int* in_sizes, int n_in,
                              void* d_out, int out_size, void* d_ws, size_t ws_size,
                              hipStream_t stream) {
  const float* x = (const float*)d_in[0];
  const float* coeffs = (const float*)d_in[1];
  const float* base_w = (const float*)d_in[2];
  float* out = (float*)d_out;

  uint2* P = (uint2*)d_ws;
  char* Wt = (char*)d_ws + P_BYTES;
  unsigned short* part = (unsigned short*)((char*)d_ws + P_BYTES + WT_BYTES);

  pack_fused_kernel<<<PACK_BLKS + WPACK_BLKS, 256, 0, stream>>>(x, P, coeffs, base_w, Wt);

  if (ws_size >= WS_NEED) {
    kan_gemm<false><<<dim3(B_DIM / BM, OUT_DIM / BN, KSPLIT), 256, 0, stream>>>(P, Wt, part, out);
    reduce_kernel<<<(int)(PART_ELEMS / 8 / 256), 256, 0, stream>>>((const uint4*)part, (v4f*)out);
  } else {
    zero_out_kernel<<<(int)((PART_ELEMS * 4) / 4096), 256, 0, stream>>>((uint4*)out);
    kan_gemm<true><<<dim3(B_DIM / BM, OUT_DIM / BN, KSPLIT), 256, 0, stream>>>(P, Wt, part, out);
  }
}

// Round 12
// 176.453 us; speedup vs baseline: 1.1001x; 1.0231x over previous
//
#include <hip/hip_runtime.h>
#include <stdint.h>

// MatrixKAN as dense bf16 MFMA GEMM over expanded interpolation basis.
// Per feature slots [0..20]=hat (2 nonzero), 21=silu(xc) (pairs base_w), 22..23=pad.
// K = 512*24 = 12288. Plane-major A tile in LDS (plane = 16B chunk column of 128
// rows); B fragments load directly from global Wt (R11: slab layout == frag
// layout, L2-served). KSPLIT=3: 768 blocks = 3/CU packed. bf16 split-K partials.
// R12: incremental A staging -- tile zeroed ONCE in prologue; per iter each lane
// clears its previous 2 hat slots (cached addresses) and writes 3 new b16 values.
// Cuts LDS writes 25.5KB->1.3KB per block-iter (LDS pipe 2647->~1776 cyc/CU/iter
// vs 2794 MFMA floor). Contents bit-identical to R10/R11 staging.
// No fences (R7), no NT stores (R5).

typedef short v8s __attribute__((ext_vector_type(8)));
typedef float v4f __attribute__((ext_vector_type(4)));

#define B_DIM 8192
#define IN_DIM 512
#define OUT_DIM 512
#define G_DIM 20
#define FPT 4                        // features per K-tile
#define KT_TOTAL (IN_DIM / FPT)      // 128 K-tiles
#define KSPLIT 3
#define BM 128
#define BN 128
#define CHUNKS 12                    // 16B chunks per tile-row (3 per feature)
#define PLANE 2048                   // 128 rows * 16B per chunk-plane
#define TILE_BYTES (CHUNKS * PLANE)  // 24 KB

#define P_BYTES ((size_t)IN_DIM * B_DIM * 8)                          // 33.55 MB
#define WT_BYTES ((size_t)(OUT_DIM / BN) * KT_TOTAL * TILE_BYTES)     // 12.58 MB
#define PART_ELEMS ((size_t)B_DIM * OUT_DIM)
#define WS_NEED (P_BYTES + WT_BYTES + (size_t)KSPLIT * PART_ELEMS * 2)

#define PACK_BLKS ((B_DIM / 64) * (IN_DIM / 64))   // 1024
#define WPACK_BLKS ((OUT_DIM * IN_DIM) / 256)      // 1024

static __device__ __forceinline__ unsigned f2bf(float f) {
  unsigned u = __builtin_bit_cast(unsigned, f);
  return (u + 0x7fffu + ((u >> 16) & 1u)) >> 16;   // RNE bf16
}

static __device__ __forceinline__ float bflo(unsigned u) {   // bf16 in low 16
  return __builtin_bit_cast(float, u << 16);
}
static __device__ __forceinline__ float bfhi(unsigned u) {   // bf16 in high 16
  return __builtin_bit_cast(float, u & 0xffff0000u);
}

__global__ void zero_out_kernel(uint4* __restrict__ out) {
  out[(size_t)blockIdx.x * 256 + threadIdx.x] = uint4{0u, 0u, 0u, 0u};
}

// Fused input-pack. Blocks [0, PACK_BLKS): x[b][i] -> P[i][b] packed
// {.x = bf16(1-t)|bf16(t)<<16, .y = idx|bf16(silu)<<16} via LDS transpose.
// Blocks [PACK_BLKS, +WPACK_BLKS): coeffs/base_w -> Wt plane-major 24KB slabs
// (slab (n_blk,kt): plane 3f+cf = slots 8cf..8cf+7 of feature kt*4+f, row=o&127).
__global__ void pack_fused_kernel(const float* __restrict__ x, uint2* __restrict__ P,
                                  const float* __restrict__ coeffs,
                                  const float* __restrict__ base_w,
                                  char* __restrict__ Wt) {
  __shared__ uint2 tile[64 * 65];
  const int t = threadIdx.x;
  if (blockIdx.x < PACK_BLKS) {
    const int b0 = (blockIdx.x & (B_DIM / 64 - 1)) * 64;
    const int i0 = (blockIdx.x / (B_DIM / 64)) * 64;
    const int tr = t >> 6;
    const int tc = t & 63;
#pragma unroll
    for (int it = 0; it < 16; ++it) {
      int br = it * 4 + tr;
      float xv = x[(size_t)(b0 + br) * IN_DIM + i0 + tc];
      float xc = fminf(fmaxf(xv, -1.0f), 1.0f);
      float xg = (xc + 1.0f) * 10.0f;           // (xc+1)*0.5*G
      int idx = (int)floorf(xg);
      idx = idx < 0 ? 0 : (idx > G_DIM - 1 ? G_DIM - 1 : idx);
      float tt = xg - (float)idx;
      float sl = xc / (1.0f + __expf(-xc));     // silu(clipped x)
      uint2 pv;
      pv.x = f2bf(1.0f - tt) | (f2bf(tt) << 16);
      pv.y = (unsigned)idx | (f2bf(sl) << 16);
      tile[tc * 65 + br] = pv;
    }
    __syncthreads();
#pragma unroll
    for (int it = 0; it < 16; ++it) {
      int ir = it * 4 + tr;
      P[(size_t)(i0 + ir) * B_DIM + b0 + tc] = tile[ir * 65 + tc];
    }
  } else {
    const unsigned u = (blockIdx.x - PACK_BLKS) * 256 + t;
    const int s = u >> 9;            // slab = n_blk*KT_TOTAL + kt
    const int w = u & 511;
    const int row = w >> 2;          // o & 127
    const int f = w & 3;
    const int n_blk = s / KT_TOTAL;
    const int kt = s - n_blk * KT_TOTAL;
    const int o = n_blk * 128 + row;
    const int i = kt * 4 + f;
    const size_t g = (size_t)o * IN_DIM + i;
    const float* c = coeffs + g * 21;
    float cf[21];
#pragma unroll
    for (int j = 0; j < 21; ++j) cf[j] = c[j];
    float bw = base_w[g];
    unsigned d[12];
#pragma unroll
    for (int j = 0; j < 10; ++j) d[j] = f2bf(cf[2 * j]) | (f2bf(cf[2 * j + 1]) << 16);
    d[10] = f2bf(cf[20]) | (f2bf(bw) << 16);  // slots 20, 21(=base_w)
    d[11] = 0u;                               // slots 22,23 pad
    char* slab = Wt + (size_t)s * TILE_BYTES;
#pragma unroll
    for (int p = 0; p < 3; ++p)
      *(uint4*)(slab + (3 * f + p) * PLANE + row * 16) =
          uint4{d[4 * p], d[4 * p + 1], d[4 * p + 2], d[4 * p + 3]};
  }
}

// out = p0+p1+p2: bf16 partial streams (8 per uint4), fp32 accumulate + store.
__global__ void reduce_kernel(const uint4* __restrict__ p, v4f* __restrict__ out) {
  size_t i = (size_t)blockIdx.x * 256 + threadIdx.x;
  const size_t q = PART_ELEMS / 8;
  uint4 a = p[i], b = p[i + q], c = p[i + 2 * q];
  v4f lo, hi;
  lo[0] = bflo(a.x) + bflo(b.x) + bflo(c.x);
  hi[0] = bfhi(a.x) + bfhi(b.x) + bfhi(c.x);
  lo[1] = bflo(a.y) + bflo(b.y) + bflo(c.y);
  hi[1] = bfhi(a.y) + bfhi(b.y) + bfhi(c.y);
  lo[2] = bflo(a.z) + bflo(b.z) + bflo(c.z);
  hi[2] = bfhi(a.z) + bfhi(b.z) + bfhi(c.z);
  lo[3] = bflo(a.w) + bflo(b.w) + bflo(c.w);
  hi[3] = bfhi(a.w) + bfhi(b.w) + bfhi(c.w);
  v4f o0 = {lo[0], hi[0], lo[1], hi[1]};
  v4f o1 = {lo[2], hi[2], lo[3], hi[3]};
  out[2 * i] = o0;
  out[2 * i + 1] = o1;
}

// slot -> byte offset within a lane's row slice (plane-major)
static __device__ __forceinline__ int slot_off(int slot) {
  return ((slot >> 3) << 11) + ((slot & 7) << 1);   // plane*2048 + within-chunk
}

template <bool ATOMIC>
__global__ __launch_bounds__(256, 3) void kan_gemm(const uint2* __restrict__ P,
                                                   const char* __restrict__ Wt,
                                                   unsigned short* __restrict__ part,
                                                   float* __restrict__ outA) {
  __shared__ uint4 lds4[TILE_BYTES / 16];   // 24KB A tile only (plane-major)
  char* Ab = (char*)lds4;
  const int t = threadIdx.x;
  const int lane = t & 63;
  const int wv = t >> 6;               // 4 waves, 2x2 grid of 64x64 tiles
  const int wm = wv >> 1, wn = wv & 1;
  const int b0 = blockIdx.x * BM;
  const int n_blk = blockIdx.y;
  const int z = blockIdx.z;
  const int kt0 = (z * KT_TOTAL) / KSPLIT;          // 0,42,85
  const int ktend = ((z + 1) * KT_TOTAL) / KSPLIT;  // 42,85,128

  v4f acc[4][4];
  const v4f z4 = {0.f, 0.f, 0.f, 0.f};
#pragma unroll
  for (int ii = 0; ii < 4; ++ii)
#pragma unroll
    for (int jj = 0; jj < 4; ++jj) acc[ii][jj] = z4;

  // prologue: zero the whole A tile once (1536 uint4 / 256 threads = 6 each)
  {
    const uint4 zz = {0u, 0u, 0u, 0u};
#pragma unroll
    for (int j = 0; j < 6; ++j) lds4[t + 256 * j] = zz;
  }

  // A-gen: wave wv owns feature wv (planes 3wv..3wv+2); lane owns rows lane, lane+64
  char* abase0 = Ab + 3 * wv * PLANE + lane * 16;
  char* abase1 = Ab + 3 * wv * PLANE + (lane + 64) * 16;
  uint2 pv0 = P[(size_t)(kt0 * 4 + wv) * B_DIM + b0 + lane];
  uint2 pv1 = P[(size_t)(kt0 * 4 + wv) * B_DIM + b0 + lane + 64];
  // cached clear addresses: init to current idx (clearing zeroed slots = no-op)
  char *c0a, *c0b, *c1a, *c1b;
  {
    int i0x = (int)(pv0.y & 0xffffu);
    c0a = abase0 + slot_off(i0x);
    c0b = abase0 + slot_off(i0x + 1);
    int i1x = (int)(pv1.y & 0xffffu);
    c1a = abase1 + slot_off(i1x);
    c1b = abase1 + slot_off(i1x + 1);
  }

  const int r16 = lane & 15;
  const int q16 = lane >> 4;

  // B frag global addresses: uint4 index chunk*128 + row (row = wn*64+cn*16+r16)
  const uint4* wbase = (const uint4*)(Wt + (size_t)n_blk * KT_TOTAL * TILE_BYTES);
  int bidx[3][4];
#pragma unroll
  for (int s = 0; s < 3; ++s)
#pragma unroll
    for (int cn = 0; cn < 4; ++cn)
      bidx[s][cn] = (s * 4 + q16) * 128 + wn * 64 + cn * 16 + r16;

  for (int kt = kt0; kt < ktend; ++kt) {
    __syncthreads();   // previous compute done (and prologue zero on iter 0)

    // B frags for this kt: 12x buffer_load_dwordx4 straight from L1/L2
    const uint4* wsrc = wbase + (size_t)kt * (TILE_BYTES / 16);
    uint4 bv[3][4];
#pragma unroll
    for (int s = 0; s < 3; ++s)
#pragma unroll
      for (int cn = 0; cn < 4; ++cn)
        bv[s][cn] = wsrc[bidx[s][cn]];

    // prefetch next P (in flight across barrier + compute)
    const int ktn = (kt + 1 < ktend) ? kt + 1 : kt;
    uint2 pn0 = P[(size_t)(ktn * 4 + wv) * B_DIM + b0 + lane];
    uint2 pn1 = P[(size_t)(ktn * 4 + wv) * B_DIM + b0 + lane + 64];

    // incremental A stage: clear previous hat slots, write new w0/w1/silu
    {
      *(unsigned short*)c0a = 0;
      *(unsigned short*)c0b = 0;
      int idx = (int)(pv0.y & 0xffffu);
      char* wa = abase0 + slot_off(idx);
      char* wb = abase0 + slot_off(idx + 1);
      *(unsigned short*)wa = (unsigned short)pv0.x;
      *(unsigned short*)wb = (unsigned short)(pv0.x >> 16);
      *(unsigned short*)(abase0 + 2 * PLANE + 10) = (unsigned short)(pv0.y >> 16);
      c0a = wa; c0b = wb;
    }
    {
      *(unsigned short*)c1a = 0;
      *(unsigned short*)c1b = 0;
      int idx = (int)(pv1.y & 0xffffu);
      char* wa = abase1 + slot_off(idx);
      char* wb = abase1 + slot_off(idx + 1);
      *(unsigned short*)wa = (unsigned short)pv1.x;
      *(unsigned short*)wb = (unsigned short)(pv1.x >> 16);
      *(unsigned short*)(abase1 + 2 * PLANE + 10) = (unsigned short)(pv1.y >> 16);
      c1a = wa; c1b = wb;
    }
    pv0 = pn0;
    pv1 = pn1;

    __syncthreads();   // drains A ds_writes (and the B/P loads)

    // compute: 3 K32-steps, 16 MFMA each per wave; A from LDS, B from regs
#pragma unroll
    for (int s = 0; s < 3; ++s) {
      const int chunk = s * 4 + q16;   // plane index; k = chunk*8 + j
      v8s af[4];
#pragma unroll
      for (int rm = 0; rm < 4; ++rm) {
        int row = wm * 64 + rm * 16 + r16;
        af[rm] = *(const v8s*)(Ab + chunk * PLANE + row * 16);
      }
#pragma unroll
      for (int rm = 0; rm < 4; ++rm)
#pragma unroll
        for (int cn = 0; cn < 4; ++cn)
          acc[rm][cn] = __builtin_amdgcn_mfma_f32_16x16x32_bf16(
              af[rm], __builtin_bit_cast(v8s, bv[s][cn]), acc[rm][cn], 0, 0, 0);
    }
  }

  // epilogue: C/D layout col=lane&15, row=(lane>>4)*4+reg (verified m89/m91)
  const int q4 = (lane >> 4) * 4;
  if (ATOMIC) {
#pragma unroll
    for (int rm = 0; rm < 4; ++rm)
#pragma unroll
      for (int cn = 0; cn < 4; ++cn)
#pragma unroll
        for (int r = 0; r < 4; ++r) {
          int row = b0 + wm * 64 + rm * 16 + q4 + r;
          int col = n_blk * BN + wn * 64 + cn * 16 + r16;
          atomicAdd(outA + (size_t)row * OUT_DIM + col, acc[rm][cn][r]);
        }
  } else {
    // bf16 partials: half the split-K write traffic; reduce re-expands to fp32
    unsigned short* mypart = part + (size_t)z * PART_ELEMS;
#pragma unroll
    for (int rm = 0; rm < 4; ++rm)
#pragma unroll
      for (int cn = 0; cn < 4; ++cn)
#pragma unroll
        for (int r = 0; r < 4; ++r) {
          int row = b0 + wm * 64 + rm * 16 + q4 + r;
          int col = n_blk * BN + wn * 64 + cn * 16 + r16;
          mypart[(size_t)row * OUT_DIM + col] = (unsigned short)f2bf(acc[rm][cn][r]);
        }
  }
}

extern "C" void kernel_launch(void* const* d_in, const int* in_sizes, int n_in,
                              void* d_out, int out_size, void* d_ws, size_t ws_size,
                              hipStream_t stream) {
  const float* x = (const float*)d_in[0];
  const float* coeffs = (const float*)d_in[1];
  const float* base_w = (const float*)d_in[2];
  float* out = (float*)d_out;

  uint2* P = (uint2*)d_ws;
  char* Wt = (char*)d_ws + P_BYTES;
  unsigned short* part = (unsigned short*)((char*)d_ws + P_BYTES + WT_BYTES);

  pack_fused_kernel<<<PACK_BLKS + WPACK_BLKS, 256, 0, stream>>>(x, P, coeffs, base_w, Wt);

  if (ws_size >= WS_NEED) {
    kan_gemm<false><<<dim3(B_DIM / BM, OUT_DIM / BN, KSPLIT), 256, 0, stream>>>(P, Wt, part, out);
    reduce_kernel<<<(int)(PART_ELEMS / 8 / 256), 256, 0, stream>>>((const uint4*)part, (v4f*)out);
  } else {
    zero_out_kernel<<<(int)((PART_ELEMS * 4) / 4096), 256, 0, stream>>>((uint4*)out);
    kan_gemm<true><<<dim3(B_DIM / BM, OUT_DIM / BN, KSPLIT), 256, 0, stream>>>(P, Wt, part, out);
  }
}